// Round 13
// baseline (322.597 us; speedup 1.0000x reference)
//
#include <hip/hip_runtime.h>

#define D 128
#define MAXDEG 64
#define BIN_SHIFT 7          // 128 destination nodes per bin
#define BINCAP 2048          // mean ~1280 edges/bin, sd ~36 -> huge margin
#define EPB 8192             // edges per binning block (1024 thr x 8)

typedef short short8 __attribute__((ext_vector_type(8)));
typedef short short4v __attribute__((ext_vector_type(4)));
typedef float float4v __attribute__((ext_vector_type(4)));

__device__ __forceinline__ unsigned short f2bf(float f) {
    union { float f; unsigned u; } v; v.f = f;
    unsigned r = v.u + 0x7FFFu + ((v.u >> 16) & 1u);
    return (unsigned short)(r >> 16);
}
__device__ __forceinline__ float bflo(unsigned p) {
    union { unsigned u; float f; } v; v.u = p << 16; return v.f;
}
__device__ __forceinline__ float bfhi(unsigned p) {
    union { unsigned u; float f; } v; v.u = p & 0xFFFF0000u; return v.f;
}

// ---------------------------------------------------------------------------
// PREP: blocks [0,binGrid) bin edges; [binGrid,binGrid+64) W transpose+cvt;
//       rest: x -> bf16 + sentinel zero rows.
__global__ __launch_bounds__(1024) void prep_kernel(const int* __restrict__ row,
                                                    const int* __restrict__ col,
                                                    int* __restrict__ bincnt,
                                                    long long* __restrict__ binbuf,
                                                    int nE, int nbins, int binGrid,
                                                    const float2* __restrict__ x,
                                                    unsigned* __restrict__ xb, int nPairs,
                                                    const float* __restrict__ W1,
                                                    const float* __restrict__ W2,
                                                    unsigned short* __restrict__ Wt1,
                                                    unsigned short* __restrict__ Wt2,
                                                    unsigned* __restrict__ hb, int n) {
    __shared__ int bcnt[1024];
    __shared__ int bbase[1024];
    const int t = threadIdx.x;

    if (blockIdx.x < (unsigned)binGrid) {
        const int e0 = blockIdx.x * EPB + t * 8;
        if (t < nbins) bcnt[t] = 0;
        __syncthreads();

        int rr[8], cc[8], bin[8], pos[8];
        if (e0 + 8 <= nE) {
            int4 r0 = *(const int4*)&row[e0];
            int4 r1 = *(const int4*)&row[e0 + 4];
            int4 c0 = *(const int4*)&col[e0];
            int4 c1 = *(const int4*)&col[e0 + 4];
            rr[0] = r0.x; rr[1] = r0.y; rr[2] = r0.z; rr[3] = r0.w;
            rr[4] = r1.x; rr[5] = r1.y; rr[6] = r1.z; rr[7] = r1.w;
            cc[0] = c0.x; cc[1] = c0.y; cc[2] = c0.z; cc[3] = c0.w;
            cc[4] = c1.x; cc[5] = c1.y; cc[6] = c1.z; cc[7] = c1.w;
            #pragma unroll
            for (int k = 0; k < 8; ++k) {
                bin[k] = rr[k] >> BIN_SHIFT;
                pos[k] = atomicAdd(&bcnt[bin[k]], 1);
            }
        } else {
            #pragma unroll
            for (int k = 0; k < 8; ++k) {
                int e = e0 + k;
                if (e < nE) {
                    rr[k] = row[e]; cc[k] = col[e];
                    bin[k] = rr[k] >> BIN_SHIFT;
                    pos[k] = atomicAdd(&bcnt[bin[k]], 1);
                } else { pos[k] = -1; bin[k] = 0; rr[k] = 0; cc[k] = 0; }
            }
        }
        __syncthreads();

        if (t < nbins) {
            int c = bcnt[t];
            bbase[t] = (c > 0) ? atomicAdd(&bincnt[t << 4], c) : 0;
        }
        __syncthreads();

        #pragma unroll
        for (int k = 0; k < 8; ++k) {
            if (pos[k] >= 0) {
                int slot = bbase[bin[k]] + pos[k];
                if (slot < BINCAP)
                    binbuf[(size_t)bin[k] * BINCAP + slot] =
                        ((long long)cc[k] << 32) | (unsigned)rr[k];
            }
        }
    } else if (blockIdx.x < (unsigned)(binGrid + 64)) {
        int id = (blockIdx.x - binGrid) * 1024 + t;   // 0..65535
        int e = id & 32767;
        int c = e >> 8, k = e & 255;
        if (id < 32768) Wt1[c * 256 + k] = f2bf(W1[k * 128 + c]);
        else            Wt2[c * 256 + k] = f2bf(W2[k * 128 + c]);
    } else {
        int cb = blockIdx.x - binGrid - 64;
        if (cb == 0 && t < 64) {
            xb[((size_t)n << 6) + t] = 0;   // sentinel zero rows
            hb[((size_t)n << 6) + t] = 0;
        }
        int id = cb * 1024 + t;
        int stride = (gridDim.x - binGrid - 64) * 1024;
        for (int i = id; i < nPairs; i += stride) {
            float2 v = x[i];
            xb[i] = (unsigned)f2bf(v.x) | ((unsigned)f2bf(v.y) << 16);
        }
    }
}

// Phase 2: one block per bin; LDS counters; padded ELL (sentinel index n).
__global__ __launch_bounds__(256) void ellbuild_kernel(const long long* __restrict__ binbuf,
                                                       const int* __restrict__ bincnt,
                                                       int* __restrict__ cnt,
                                                       int* __restrict__ bucket, int n) {
    __shared__ int lcnt[1 << BIN_SHIFT];
    const int b = blockIdx.x, t = threadIdx.x;
    const int base = b << BIN_SHIFT;
    if (t < (1 << BIN_SHIFT)) lcnt[t] = 0;
    __syncthreads();
    int m = bincnt[b << 4];
    if (m > BINCAP) m = BINCAP;
    const long long* buf = binbuf + (size_t)b * BINCAP;
    for (int j = t; j < m; j += 256) {
        long long pk = buf[j];
        int r = (int)pk;            // low 32
        int c = (int)(pk >> 32);    // high 32
        int pos = atomicAdd(&lcnt[r - base], 1);
        if (pos < MAXDEG) bucket[((size_t)r << 6) + pos] = c;
    }
    __syncthreads();
    if (t < (1 << BIN_SHIFT)) {
        int node = base + t;
        if (node < n) {
            int c0 = lcnt[t];
            cnt[node] = c0;                       // true degree (for 1/deg)
            int c = c0 > MAXDEG ? MAXDEG : c0;
            int cp = (c + 15) & ~15;              // pad to multiple of 16
            for (int s = c; s < cp; ++s) bucket[((size_t)node << 6) + s] = n;
        }
    }
}

// ---------------------------------------------------------------------------
// 16-wide unconditional gather-accumulate (bucket row padded with sentinel)
__device__ __forceinline__ void gather16(const unsigned* __restrict__ feat,
                                         const int* __restrict__ bk, int j, unsigned lane,
                                         float& x0, float& x1, float& x2, float& x3,
                                         float& y0, float& y1, float& y2, float& y3) {
    int4 c0 = *(const int4*)&bk[j];
    int4 c1 = *(const int4*)&bk[j + 4];
    int4 c2 = *(const int4*)&bk[j + 8];
    int4 c3 = *(const int4*)&bk[j + 12];
    unsigned v0  = feat[((unsigned)c0.x << 6) + lane];
    unsigned v1  = feat[((unsigned)c0.y << 6) + lane];
    unsigned v2  = feat[((unsigned)c0.z << 6) + lane];
    unsigned v3  = feat[((unsigned)c0.w << 6) + lane];
    unsigned v4  = feat[((unsigned)c1.x << 6) + lane];
    unsigned v5  = feat[((unsigned)c1.y << 6) + lane];
    unsigned v6  = feat[((unsigned)c1.z << 6) + lane];
    unsigned v7  = feat[((unsigned)c1.w << 6) + lane];
    unsigned v8  = feat[((unsigned)c2.x << 6) + lane];
    unsigned v9  = feat[((unsigned)c2.y << 6) + lane];
    unsigned v10 = feat[((unsigned)c2.z << 6) + lane];
    unsigned v11 = feat[((unsigned)c2.w << 6) + lane];
    unsigned v12 = feat[((unsigned)c3.x << 6) + lane];
    unsigned v13 = feat[((unsigned)c3.y << 6) + lane];
    unsigned v14 = feat[((unsigned)c3.z << 6) + lane];
    unsigned v15 = feat[((unsigned)c3.w << 6) + lane];
    x0 += bflo(v0);  y0 += bfhi(v0);
    x1 += bflo(v1);  y1 += bfhi(v1);
    x2 += bflo(v2);  y2 += bfhi(v2);
    x3 += bflo(v3);  y3 += bfhi(v3);
    x0 += bflo(v4);  y0 += bfhi(v4);
    x1 += bflo(v5);  y1 += bfhi(v5);
    x2 += bflo(v6);  y2 += bfhi(v6);
    x3 += bflo(v7);  y3 += bfhi(v7);
    x0 += bflo(v8);  y0 += bfhi(v8);
    x1 += bflo(v9);  y1 += bfhi(v9);
    x2 += bflo(v10); y2 += bfhi(v10);
    x3 += bflo(v11); y3 += bfhi(v11);
    x0 += bflo(v12); y0 += bfhi(v12);
    x1 += bflo(v13); y1 += bfhi(v13);
    x2 += bflo(v14); y2 += bfhi(v14);
    x3 += bflo(v15); y3 += bfhi(v15);
}

__device__ __forceinline__ short8 loadB(const unsigned short* __restrict__ wp, int ks, int g) {
    short4v lo = *(const short4v*)(wp + ks * 32 + 4 * g);
    short4v hi = *(const short4v*)(wp + ks * 32 + 16 + 4 * g);
    return __builtin_shufflevector(lo, hi, 0, 1, 2, 3, 4, 5, 6, 7);
}

// ---------------------------------------------------------------------------
// FUSED gather + GEMM. Block = 1024 thr (16 waves), 32 output rows, 16KB LDS.
// Wave w: (a) stages self rows 2w,2w+1 into LDS (swizzled); (b) gathers agg
// for nodes 2w,2w+1 (16-wide unconditional, same parallelism as standalone
// agg); writes agg rows into LDS. Barrier. (c) computes ONE 16x16 C fragment
// (rf=w&1, cf=w>>1) over K=256. Barrier. (d) coalesced epilogue via LDS reuse.
template <bool RELU, bool OUTF32>
__global__ __launch_bounds__(1024) void sage_fused(const unsigned short* __restrict__ selfb, // [n+1][128] bf16
                                                   const unsigned* __restrict__ featd,       // dword view
                                                   const int* __restrict__ cnt,
                                                   const int* __restrict__ bucket,           // [n][64] padded
                                                   const unsigned short* __restrict__ Wtb,   // [128][256]
                                                   const float* __restrict__ bias,           // [128]
                                                   float* __restrict__ outf,
                                                   unsigned short* __restrict__ outb,
                                                   int n) {
    // [0,8K): self tile 32x128 bf16 (swz) | [8K,16K): agg tile 32x128 bf16 (swz)
    // after barrier2: whole 16KB reused as output tile
    __shared__ short Alds[32 * 256];
    const int tid  = threadIdx.x;
    const int w    = tid >> 6;          // 0..15
    const int lane = tid & 63;
    const int r15  = lane & 15, g = lane >> 4;
    const int rowbase = blockIdx.x * 32;

    // ---- (a) stage self rows 2w, 2w+1: 8B per lane, swizzled 16B chunks ----
    {
        int lrow = lane >> 5;                 // 0..1
        int lw   = lane & 31;                 // b64 word within row (32 x 8B)
        int row  = 2 * w + lrow;
        int rowG = rowbase + row; if (rowG >= n) rowG = n;   // sentinel row ok
        short4v v = *(const short4v*)(selfb + (size_t)rowG * D + lw * 4);
        int ch = (lw >> 1) ^ (row & 7);
        *(short4v*)((char*)Alds + row * 256 + ch * 16 + (lw & 1) * 8) = v;
    }

    // ---- (b) gather agg for nodes iA=rowbase+2w, iB=+1 ----
    {
        int iA = rowbase + 2 * w, iB = iA + 1;
        int dtA = 0, dpA = 0, dtB = 0, dpB = 0;
        if (iA < n) { dtA = cnt[iA]; int d = dtA > MAXDEG ? MAXDEG : dtA; dpA = (d + 15) & ~15; }
        if (iB < n) { dtB = cnt[iB]; int d = dtB > MAXDEG ? MAXDEG : dtB; dpB = (d + 15) & ~15; }
        const int* bkA = bucket + ((size_t)iA << 6);
        const int* bkB = bucket + ((size_t)iB << 6);

        float ax0=0,ax1=0,ax2=0,ax3=0, ay0=0,ay1=0,ay2=0,ay3=0;
        float bx0=0,bx1=0,bx2=0,bx3=0, by0=0,by1=0,by2=0,by3=0;
        int jm = dpA > dpB ? dpA : dpB;
        for (int j = 0; j < jm; j += 16) {
            if (j < dpA) gather16(featd, bkA, j, (unsigned)lane, ax0,ax1,ax2,ax3, ay0,ay1,ay2,ay3);
            if (j < dpB) gather16(featd, bkB, j, (unsigned)lane, bx0,bx1,bx2,bx3, by0,by1,by2,by3);
        }
        // agg dword of lane covers cols 2*lane..2*lane+1; chunk = lane>>2
        if (iA < n) {
            float inv = (dtA > 0) ? 1.0f / (float)dtA : 0.0f;
            unsigned pair = (unsigned)f2bf(((ax0+ax1)+(ax2+ax3)) * inv)
                          | ((unsigned)f2bf(((ay0+ay1)+(ay2+ay3)) * inv) << 16);
            int row = 2 * w;
            int ch = (lane >> 2) ^ (row & 7);
            *(unsigned*)((char*)Alds + 8192 + row * 256 + ch * 16 + (lane & 3) * 4) = pair;
        }
        if (iB < n) {
            float inv = (dtB > 0) ? 1.0f / (float)dtB : 0.0f;
            unsigned pair = (unsigned)f2bf(((bx0+bx1)+(bx2+bx3)) * inv)
                          | ((unsigned)f2bf(((by0+by1)+(by2+by3)) * inv) << 16);
            int row = 2 * w + 1;
            int ch = (lane >> 2) ^ (row & 7);
            *(unsigned*)((char*)Alds + 8192 + row * 256 + ch * 16 + (lane & 3) * 4) = pair;
        }
    }

    __syncthreads();

    // ---- (c) GEMM: wave w computes C fragment rf=w&1 (rows), cf=w>>1 (cols) ----
    const int rf = w & 1;
    const int cf = w >> 1;
    const int colbase = cf * 16;
    const unsigned short* wp = Wtb + (size_t)(colbase + r15) * 256;
    float bv = bias[colbase + r15];
    float4v acc = (float4v){bv, bv, bv, bv};

    const int rr = rf * 16 + r15;               // A row this lane reads
    const int sw = (rr & 7) << 4;
    const char* prS = (const char*)Alds + rr * 256;          // self half
    const char* prG = (const char*)Alds + 8192 + rr * 256;   // agg half
    #pragma unroll
    for (int ks = 0; ks < 8; ++ks) {
        const char* pr = (ks < 4) ? prS : prG;
        int ko = (ks & 3) * 64 + 8 * g;
        short4v lo = *(const short4v*)(pr + (ko ^ sw));
        short4v hi = *(const short4v*)(pr + ((ko + 32) ^ sw));
        short8 af = __builtin_shufflevector(lo, hi, 0, 1, 2, 3, 4, 5, 6, 7);
        short8 bf = loadB(wp, ks, g);
        acc = __builtin_amdgcn_mfma_f32_16x16x32_bf16(af, bf, acc, 0, 0, 0);
    }

    // ---- (d) epilogue via LDS reuse: coalesced vector stores ----
    __syncthreads();
    if (OUTF32) {
        float* ol = (float*)Alds;       // 32 x 128 f32 = 16KB
        #pragma unroll
        for (int r = 0; r < 4; ++r) {
            float v = acc[r];
            if (RELU) v = (v > 0.0f) ? v : 0.0f;
            ol[(rf * 16 + g * 4 + r) * 128 + colbase + r15] = v;
        }
        __syncthreads();
        int r = tid >> 5, ch = tid & 31;        // 1024 thr: 32 rows x 32 f32x4
        int rowG = rowbase + r;
        if (rowG < n)
            *(float4v*)&outf[(size_t)rowG * D + ch * 4] = *(const float4v*)&ol[r * 128 + ch * 4];
    } else {
        unsigned short* ol = (unsigned short*)Alds;   // 32 x 128 bf16 = 8KB
        #pragma unroll
        for (int r = 0; r < 4; ++r) {
            float v = acc[r];
            if (RELU) v = (v > 0.0f) ? v : 0.0f;
            ol[(rf * 16 + g * 4 + r) * 128 + colbase + r15] = f2bf(v);
        }
        __syncthreads();
        if (tid < 512) {
            int r = tid >> 4, ch = tid & 15;    // 512 thr: 32 rows x 16 short8
            int rowG = rowbase + r;
            if (rowG < n)
                *(short8*)&outb[(size_t)rowG * D + ch * 8] = *(const short8*)&ol[r * 128 + ch * 8];
        }
    }
}

// ---------------------------------------------------------------------------
extern "C" void kernel_launch(void* const* d_in, const int* in_sizes, int n_in,
                              void* d_out, int out_size, void* d_ws, size_t ws_size,
                              hipStream_t stream) {
    const float* x  = (const float*)d_in[0];
    const int*   ei = (const int*)d_in[1];
    const float* W1 = (const float*)d_in[2];
    const float* b1 = (const float*)d_in[3];
    const float* W2 = (const float*)d_in[4];
    const float* b2 = (const float*)d_in[5];
    float* out = (float*)d_out;

    const int n  = in_sizes[0] / D;   // 100000
    const int nE = in_sizes[1] / 2;   // 1000000
    const int* row = ei;
    const int* col = ei + nE;
    const int nbins = (n + (1 << BIN_SHIFT) - 1) >> BIN_SHIFT;   // 782

    auto aup = [](size_t v) { return (v + 63) & ~(size_t)63; };
    int* wsI = (int*)d_ws;
    size_t o = 0;
    int* cnt    = wsI + o; o = aup(o + (size_t)n);
    int* bucket = wsI + o; o = aup(o + ((size_t)n << 6));               // [n][64]
    unsigned* xb   = (unsigned*)(wsI + o); o = aup(o + (size_t)(n + 1) * 64); // +1 sentinel row
    unsigned* hb   = (unsigned*)(wsI + o); o = aup(o + (size_t)(n + 1) * 64);
    unsigned short* Wt1 = (unsigned short*)(wsI + o); o = aup(o + 16384);
    unsigned short* Wt2 = (unsigned short*)(wsI + o); o = aup(o + 16384);
    int* bincnt = wsI + o; o = aup(o + (size_t)nbins * 16);             // 1 counter / 64B
    long long* binbuf = (long long*)(wsI + o); o = aup(o + (size_t)nbins * BINCAP * 2);

    const int B = 256;
    const int binGrid = (nE + EPB - 1) / EPB;                           // 123
    const int fGrid   = (n + 31) / 32;                                  // 3125

    // prep: binning + W transpose + x conversion, one kernel
    hipMemsetAsync(bincnt, 0, (size_t)nbins * 16 * sizeof(int), stream);
    prep_kernel<<<binGrid + 64 + 512, 1024, 0, stream>>>(
        row, col, bincnt, binbuf, nE, nbins, binGrid,
        (const float2*)x, xb, n * 64, W1, W2, Wt1, Wt2, hb, n);
    ellbuild_kernel<<<nbins, B, 0, stream>>>(binbuf, bincnt, cnt, bucket, n);

    // layer 1 (fused gather+GEMM), bf16 out -> hb
    sage_fused<true, false><<<fGrid, 1024, 0, stream>>>(
        (const unsigned short*)xb, xb, cnt, bucket, Wt1, b1,
        nullptr, (unsigned short*)hb, n);

    // layer 2 (fused gather+GEMM), f32 out -> d_out
    sage_fused<false, true><<<fGrid, 1024, 0, stream>>>(
        (const unsigned short*)hb, hb, cnt, bucket, Wt2, b2,
        out, nullptr, n);
}

// Round 14
// 194.217 us; speedup vs baseline: 1.6610x; 1.6610x over previous
//
#include <hip/hip_runtime.h>

#define D 128
#define MAXDEG 64
#define BIN_SHIFT 7          // 128 destination nodes per bin
#define BINCAP 2048          // mean ~1280 edges/bin, sd ~36 -> huge margin
#define EPB 8192             // edges per binning block (1024 thr x 8)

typedef short short8 __attribute__((ext_vector_type(8)));
typedef short short4v __attribute__((ext_vector_type(4)));
typedef float float4v __attribute__((ext_vector_type(4)));

__device__ __forceinline__ unsigned short f2bf(float f) {
    union { float f; unsigned u; } v; v.f = f;
    unsigned r = v.u + 0x7FFFu + ((v.u >> 16) & 1u);
    return (unsigned short)(r >> 16);
}
__device__ __forceinline__ float bflo(unsigned p) {
    union { unsigned u; float f; } v; v.u = p << 16; return v.f;
}
__device__ __forceinline__ float bfhi(unsigned p) {
    union { unsigned u; float f; } v; v.u = p & 0xFFFF0000u; return v.f;
}

// ---------------------------------------------------------------------------
// PREP: blocks [0,binGrid) bin edges; [binGrid,binGrid+64) W transpose+cvt;
//       rest: x -> bf16 + sentinel zero rows.
__global__ __launch_bounds__(1024) void prep_kernel(const int* __restrict__ row,
                                                    const int* __restrict__ col,
                                                    int* __restrict__ bincnt,
                                                    long long* __restrict__ binbuf,
                                                    int nE, int nbins, int binGrid,
                                                    const float2* __restrict__ x,
                                                    unsigned* __restrict__ xb, int nPairs,
                                                    const float* __restrict__ W1,
                                                    const float* __restrict__ W2,
                                                    unsigned short* __restrict__ Wt1,
                                                    unsigned short* __restrict__ Wt2,
                                                    unsigned* __restrict__ hb, int n) {
    __shared__ int bcnt[1024];
    __shared__ int bbase[1024];
    const int t = threadIdx.x;

    if (blockIdx.x < (unsigned)binGrid) {
        const int e0 = blockIdx.x * EPB + t * 8;
        if (t < nbins) bcnt[t] = 0;
        __syncthreads();

        int rr[8], cc[8], bin[8], pos[8];
        if (e0 + 8 <= nE) {
            int4 r0 = *(const int4*)&row[e0];
            int4 r1 = *(const int4*)&row[e0 + 4];
            int4 c0 = *(const int4*)&col[e0];
            int4 c1 = *(const int4*)&col[e0 + 4];
            rr[0] = r0.x; rr[1] = r0.y; rr[2] = r0.z; rr[3] = r0.w;
            rr[4] = r1.x; rr[5] = r1.y; rr[6] = r1.z; rr[7] = r1.w;
            cc[0] = c0.x; cc[1] = c0.y; cc[2] = c0.z; cc[3] = c0.w;
            cc[4] = c1.x; cc[5] = c1.y; cc[6] = c1.z; cc[7] = c1.w;
            #pragma unroll
            for (int k = 0; k < 8; ++k) {
                bin[k] = rr[k] >> BIN_SHIFT;
                pos[k] = atomicAdd(&bcnt[bin[k]], 1);
            }
        } else {
            #pragma unroll
            for (int k = 0; k < 8; ++k) {
                int e = e0 + k;
                if (e < nE) {
                    rr[k] = row[e]; cc[k] = col[e];
                    bin[k] = rr[k] >> BIN_SHIFT;
                    pos[k] = atomicAdd(&bcnt[bin[k]], 1);
                } else { pos[k] = -1; bin[k] = 0; rr[k] = 0; cc[k] = 0; }
            }
        }
        __syncthreads();

        if (t < nbins) {
            int c = bcnt[t];
            bbase[t] = (c > 0) ? atomicAdd(&bincnt[t << 4], c) : 0;
        }
        __syncthreads();

        #pragma unroll
        for (int k = 0; k < 8; ++k) {
            if (pos[k] >= 0) {
                int slot = bbase[bin[k]] + pos[k];
                if (slot < BINCAP)
                    binbuf[(size_t)bin[k] * BINCAP + slot] =
                        ((long long)cc[k] << 32) | (unsigned)rr[k];
            }
        }
    } else if (blockIdx.x < (unsigned)(binGrid + 64)) {
        int id = (blockIdx.x - binGrid) * 1024 + t;   // 0..65535
        int e = id & 32767;
        int c = e >> 8, k = e & 255;
        if (id < 32768) Wt1[c * 256 + k] = f2bf(W1[k * 128 + c]);
        else            Wt2[c * 256 + k] = f2bf(W2[k * 128 + c]);
    } else {
        int cb = blockIdx.x - binGrid - 64;
        if (cb == 0 && t < 64) {
            xb[((size_t)n << 6) + t] = 0;   // sentinel zero rows
            hb[((size_t)n << 6) + t] = 0;
        }
        int id = cb * 1024 + t;
        int stride = (gridDim.x - binGrid - 64) * 1024;
        for (int i = id; i < nPairs; i += stride) {
            float2 v = x[i];
            xb[i] = (unsigned)f2bf(v.x) | ((unsigned)f2bf(v.y) << 16);
        }
    }
}

// Phase 2: one block per bin; LDS counters; padded ELL (sentinel index n).
__global__ __launch_bounds__(256) void ellbuild_kernel(const long long* __restrict__ binbuf,
                                                       const int* __restrict__ bincnt,
                                                       int* __restrict__ cnt,
                                                       int* __restrict__ bucket, int n) {
    __shared__ int lcnt[1 << BIN_SHIFT];
    const int b = blockIdx.x, t = threadIdx.x;
    const int base = b << BIN_SHIFT;
    if (t < (1 << BIN_SHIFT)) lcnt[t] = 0;
    __syncthreads();
    int m = bincnt[b << 4];
    if (m > BINCAP) m = BINCAP;
    const long long* buf = binbuf + (size_t)b * BINCAP;
    for (int j = t; j < m; j += 256) {
        long long pk = buf[j];
        int r = (int)pk;            // low 32
        int c = (int)(pk >> 32);    // high 32
        int pos = atomicAdd(&lcnt[r - base], 1);
        if (pos < MAXDEG) bucket[((size_t)r << 6) + pos] = c;
    }
    __syncthreads();
    if (t < (1 << BIN_SHIFT)) {
        int node = base + t;
        if (node < n) {
            int c0 = lcnt[t];
            cnt[node] = c0;                       // true degree (for 1/deg)
            int c = c0 > MAXDEG ? MAXDEG : c0;
            int cp = (c + 15) & ~15;              // pad to multiple of 16
            for (int s = c; s < cp; ++s) bucket[((size_t)node << 6) + s] = n;
        }
    }
}

// ---------------------------------------------------------------------------
// 16-wide unconditional gather-accumulate (bucket row padded with sentinel)
__device__ __forceinline__ void gather16(const unsigned* __restrict__ feat,
                                         const int* __restrict__ bk, int j, unsigned lane,
                                         float& x0, float& x1, float& x2, float& x3,
                                         float& y0, float& y1, float& y2, float& y3) {
    int4 c0 = *(const int4*)&bk[j];
    int4 c1 = *(const int4*)&bk[j + 4];
    int4 c2 = *(const int4*)&bk[j + 8];
    int4 c3 = *(const int4*)&bk[j + 12];
    unsigned v0  = feat[((unsigned)c0.x << 6) + lane];
    unsigned v1  = feat[((unsigned)c0.y << 6) + lane];
    unsigned v2  = feat[((unsigned)c0.z << 6) + lane];
    unsigned v3  = feat[((unsigned)c0.w << 6) + lane];
    unsigned v4  = feat[((unsigned)c1.x << 6) + lane];
    unsigned v5  = feat[((unsigned)c1.y << 6) + lane];
    unsigned v6  = feat[((unsigned)c1.z << 6) + lane];
    unsigned v7  = feat[((unsigned)c1.w << 6) + lane];
    unsigned v8  = feat[((unsigned)c2.x << 6) + lane];
    unsigned v9  = feat[((unsigned)c2.y << 6) + lane];
    unsigned v10 = feat[((unsigned)c2.z << 6) + lane];
    unsigned v11 = feat[((unsigned)c2.w << 6) + lane];
    unsigned v12 = feat[((unsigned)c3.x << 6) + lane];
    unsigned v13 = feat[((unsigned)c3.y << 6) + lane];
    unsigned v14 = feat[((unsigned)c3.z << 6) + lane];
    unsigned v15 = feat[((unsigned)c3.w << 6) + lane];
    x0 += bflo(v0);  y0 += bfhi(v0);
    x1 += bflo(v1);  y1 += bfhi(v1);
    x2 += bflo(v2);  y2 += bfhi(v2);
    x3 += bflo(v3);  y3 += bfhi(v3);
    x0 += bflo(v4);  y0 += bfhi(v4);
    x1 += bflo(v5);  y1 += bfhi(v5);
    x2 += bflo(v6);  y2 += bfhi(v6);
    x3 += bflo(v7);  y3 += bfhi(v7);
    x0 += bflo(v8);  y0 += bfhi(v8);
    x1 += bflo(v9);  y1 += bfhi(v9);
    x2 += bflo(v10); y2 += bfhi(v10);
    x3 += bflo(v11); y3 += bfhi(v11);
    x0 += bflo(v12); y0 += bfhi(v12);
    x1 += bflo(v13); y1 += bfhi(v13);
    x2 += bflo(v14); y2 += bfhi(v14);
    x3 += bflo(v15); y3 += bfhi(v15);
}

// bf16 gather-mean: TWO nodes per wave, 16-wide unconditional batches.
__global__ __launch_bounds__(256) void agg_bf16_kernel(const unsigned* __restrict__ feat, // [n+1][64] dwords
                                                       const int* __restrict__ cnt,
                                                       const int* __restrict__ bucket,    // [n][64] padded
                                                       unsigned* __restrict__ agg, int n) {
    long long tid = (long long)blockIdx.x * blockDim.x + threadIdx.x;
    int w = (int)(tid >> 6);
    int iA = w * 2, iB = w * 2 + 1;
    if (iA >= n) return;
    const unsigned lane = (unsigned)tid & 63u;

    int dtA = cnt[iA];
    int dA = dtA > MAXDEG ? MAXDEG : dtA;
    int dpA = (dA + 15) & ~15;
    int dtB = 0, dpB = 0;
    if (iB < n) {
        dtB = cnt[iB];
        int dB = dtB > MAXDEG ? MAXDEG : dtB;
        dpB = (dB + 15) & ~15;
    }
    const int* bkA = bucket + ((size_t)iA << 6);
    const int* bkB = bucket + ((size_t)iB << 6);

    float ax0=0,ax1=0,ax2=0,ax3=0, ay0=0,ay1=0,ay2=0,ay3=0;
    float bx0=0,bx1=0,bx2=0,bx3=0, by0=0,by1=0,by2=0,by3=0;
    int jm = dpA > dpB ? dpA : dpB;
    for (int j = 0; j < jm; j += 16) {
        if (j < dpA) gather16(feat, bkA, j, lane, ax0,ax1,ax2,ax3, ay0,ay1,ay2,ay3);
        if (j < dpB) gather16(feat, bkB, j, lane, bx0,bx1,bx2,bx3, by0,by1,by2,by3);
    }

    float invA = (dtA > 0) ? 1.0f / (float)dtA : 0.0f;
    float rxA = ((ax0 + ax1) + (ax2 + ax3)) * invA;
    float ryA = ((ay0 + ay1) + (ay2 + ay3)) * invA;
    agg[((size_t)iA << 6) + lane] = (unsigned)f2bf(rxA) | ((unsigned)f2bf(ryA) << 16);
    if (iB < n) {
        float invB = (dtB > 0) ? 1.0f / (float)dtB : 0.0f;
        float rxB = ((bx0 + bx1) + (bx2 + bx3)) * invB;
        float ryB = ((by0 + by1) + (by2 + by3)) * invB;
        agg[((size_t)iB << 6) + lane] = (unsigned)f2bf(rxB) | ((unsigned)f2bf(ryB) << 16);
    }
}

// ---------------------------------------------------------------------------
// MFMA GEMM (round-10 structure): 256 thr (4 waves), 64 rows x 128 cols,
// K=256, 32KB LDS (XOR-swz), register staging, full 8-deep B preload.
// NEW: bf16 output goes through an LDS tile for exact coalesced stores
// (f32 stores are already 64B-exact, kept direct).
template <bool RELU, bool OUTF32>
__global__ __launch_bounds__(256) void sage_mfma(const unsigned short* __restrict__ selfb, // [n][128]
                                                 const unsigned short* __restrict__ aggb,  // [n][128]
                                                 const unsigned short* __restrict__ Wtb,   // [128][256]
                                                 const float* __restrict__ bias,           // [128]
                                                 float* __restrict__ outf,
                                                 unsigned short* __restrict__ outb,
                                                 int n) {
    __shared__ short Alds[64 * 256];
    const int tid  = threadIdx.x;
    const int wave = tid >> 6;
    const int lane = tid & 63;
    const int r15  = lane & 15, g = lane >> 4;
    const int rowbase = blockIdx.x * 64;

    #pragma unroll
    for (int it = 0; it < 8; ++it) {
        int id  = it * 256 + tid;           // 0..2047 chunk id (16B chunks)
        int row = id >> 5, cin = id & 31;
        int rowG = rowbase + row; if (rowG >= n) rowG = n - 1;
        const unsigned short* src = (cin < 16)
            ? selfb + (size_t)rowG * D + cin * 8
            : aggb  + (size_t)rowG * D + (cin - 16) * 8;
        int dchunk = cin ^ (row & 7);
        *(short8*)&Alds[row * 256 + dchunk * 8] = *(const short8*)src;
    }

    const int colbase = wave * 32;
    short8 bfr[2][8];
    #pragma unroll
    for (int cf = 0; cf < 2; ++cf) {
        const unsigned short* wp = Wtb + (size_t)(colbase + cf * 16 + r15) * 256;
        #pragma unroll
        for (int ks = 0; ks < 8; ++ks) {
            short4v lo = *(const short4v*)(wp + ks * 32 + 4 * g);
            short4v hi = *(const short4v*)(wp + ks * 32 + 16 + 4 * g);
            bfr[cf][ks] = __builtin_shufflevector(lo, hi, 0, 1, 2, 3, 4, 5, 6, 7);
        }
    }
    float bv0 = bias[colbase + r15];
    float bv1 = bias[colbase + 16 + r15];
    float4v acc[4][2];
    #pragma unroll
    for (int rf = 0; rf < 4; ++rf) {
        acc[rf][0] = (float4v){bv0, bv0, bv0, bv0};
        acc[rf][1] = (float4v){bv1, bv1, bv1, bv1};
    }

    __syncthreads();

    const int sw = (r15 & 7) << 4;
    #pragma unroll
    for (int ks = 0; ks < 8; ++ks) {
        #pragma unroll
        for (int rf = 0; rf < 4; ++rf) {
            const char* pr = (const char*)&Alds[(rf * 16 + r15) * 256];
            short4v lo = *(const short4v*)(pr + ((ks * 64 + 8 * g) ^ sw));
            short4v hi = *(const short4v*)(pr + ((ks * 64 + 8 * g + 32) ^ sw));
            short8 af = __builtin_shufflevector(lo, hi, 0, 1, 2, 3, 4, 5, 6, 7);
            acc[rf][0] = __builtin_amdgcn_mfma_f32_16x16x32_bf16(af, bfr[0][ks], acc[rf][0], 0, 0, 0);
            acc[rf][1] = __builtin_amdgcn_mfma_f32_16x16x32_bf16(af, bfr[1][ks], acc[rf][1], 0, 0, 0);
        }
    }

    if (OUTF32) {
        // direct stores: 16 consecutive f32 per 16-lane group = aligned 64B, no amp
        #pragma unroll
        for (int rf = 0; rf < 4; ++rf)
            #pragma unroll
            for (int cf = 0; cf < 2; ++cf)
                #pragma unroll
                for (int r = 0; r < 4; ++r) {
                    int row = rowbase + rf * 16 + g * 4 + r;
                    int col = colbase + cf * 16 + r15;
                    if (row < n) {
                        float v = acc[rf][cf][r];
                        if (RELU) v = (v > 0.0f) ? v : 0.0f;
                        outf[(size_t)row * D + col] = v;
                    }
                }
    } else {
        // bf16: stage in LDS (reuse A buffer), then exact row-contiguous stores
        __syncthreads();   // all waves done reading A
        unsigned short* ol = (unsigned short*)Alds;   // 64 x 128 bf16 = 16KB
        #pragma unroll
        for (int rf = 0; rf < 4; ++rf)
            #pragma unroll
            for (int cf = 0; cf < 2; ++cf)
                #pragma unroll
                for (int r = 0; r < 4; ++r) {
                    float v = acc[rf][cf][r];
                    if (RELU) v = (v > 0.0f) ? v : 0.0f;
                    ol[(rf * 16 + g * 4 + r) * 128 + colbase + cf * 16 + r15] = f2bf(v);
                }
        __syncthreads();
        #pragma unroll
        for (int it = 0; it < 4; ++it) {
            int id = it * 256 + tid;           // 0..1023: 64 rows x 16 short8-chunks
            int r = id >> 4, ch = id & 15;
            int rowG = rowbase + r;
            if (rowG < n)
                *(short8*)&outb[(size_t)rowG * D + ch * 8] = *(const short8*)&ol[r * 128 + ch * 8];
        }
    }
}

// ---------------------------------------------------------------------------
extern "C" void kernel_launch(void* const* d_in, const int* in_sizes, int n_in,
                              void* d_out, int out_size, void* d_ws, size_t ws_size,
                              hipStream_t stream) {
    const float* x  = (const float*)d_in[0];
    const int*   ei = (const int*)d_in[1];
    const float* W1 = (const float*)d_in[2];
    const float* b1 = (const float*)d_in[3];
    const float* W2 = (const float*)d_in[4];
    const float* b2 = (const float*)d_in[5];
    float* out = (float*)d_out;

    const int n  = in_sizes[0] / D;   // 100000
    const int nE = in_sizes[1] / 2;   // 1000000
    const int* row = ei;
    const int* col = ei + nE;
    const int nbins = (n + (1 << BIN_SHIFT) - 1) >> BIN_SHIFT;   // 782

    auto aup = [](size_t v) { return (v + 63) & ~(size_t)63; };
    int* wsI = (int*)d_ws;
    size_t o = 0;
    int* cnt    = wsI + o; o = aup(o + (size_t)n);
    int* bucket = wsI + o; o = aup(o + ((size_t)n << 6));               // [n][64]
    unsigned* xb   = (unsigned*)(wsI + o); o = aup(o + (size_t)(n + 1) * 64); // +1 sentinel row
    unsigned* hb   = (unsigned*)(wsI + o); o = aup(o + (size_t)(n + 1) * 64);
    unsigned* aggb = (unsigned*)(wsI + o); o = aup(o + (size_t)n * 64);
    unsigned short* Wt1 = (unsigned short*)(wsI + o); o = aup(o + 16384);
    unsigned short* Wt2 = (unsigned short*)(wsI + o); o = aup(o + 16384);
    int* bincnt = wsI + o; o = aup(o + (size_t)nbins * 16);             // 1 counter / 64B
    // binbuf overlaps aggb (dead before first agg): 782*2048*8B = 12.8MB < 25.6MB
    long long* binbuf = (long long*)aggb;

    const int B = 256;
    const int binGrid = (nE + EPB - 1) / EPB;                           // 123
    const int aggGrid = (int)((((long long)(n + 1) / 2) * 64 + B - 1) / B);
    const int mmGrid  = (n + 63) / 64;                                  // 1563

    // prep: binning + W transpose + x conversion, one kernel
    hipMemsetAsync(bincnt, 0, (size_t)nbins * 16 * sizeof(int), stream);
    prep_kernel<<<binGrid + 64 + 512, 1024, 0, stream>>>(
        row, col, bincnt, binbuf, nE, nbins, binGrid,
        (const float2*)x, xb, n * 64, W1, W2, Wt1, Wt2, hb, n);
    ellbuild_kernel<<<nbins, B, 0, stream>>>(binbuf, bincnt, cnt, bucket, n);

    // layer 1
    agg_bf16_kernel<<<aggGrid, B, 0, stream>>>(xb, cnt, bucket, aggb, n);
    sage_mfma<true, false><<<mmGrid, B, 0, stream>>>(
        (const unsigned short*)xb, (const unsigned short*)aggb, Wt1, b1,
        nullptr, (unsigned short*)hb, n);

    // layer 2
    agg_bf16_kernel<<<aggGrid, B, 0, stream>>>(hb, cnt, bucket, aggb, n);
    sage_mfma<false, true><<<mmGrid, B, 0, stream>>>(
        (const unsigned short*)hb, (const unsigned short*)aggb, Wt2, b2,
        out, nullptr, n);
}

// Round 15
// 169.258 us; speedup vs baseline: 1.9059x; 1.1475x over previous
//
#include <hip/hip_runtime.h>

#define D 128
#define MAXDEG 64
#define BIN_SHIFT 7          // 128 destination nodes per bin
#define BINCAP 2048          // mean ~1280 edges/bin, sd ~36 -> huge margin
#define EPB 8192             // edges per binning block (1024 thr x 8)

typedef short short8 __attribute__((ext_vector_type(8)));
typedef short short4v __attribute__((ext_vector_type(4)));
typedef float float4v __attribute__((ext_vector_type(4)));

__device__ __forceinline__ unsigned short f2bf(float f) {
    union { float f; unsigned u; } v; v.f = f;
    unsigned r = v.u + 0x7FFFu + ((v.u >> 16) & 1u);
    return (unsigned short)(r >> 16);
}
__device__ __forceinline__ float bflo(unsigned p) {
    union { unsigned u; float f; } v; v.u = p << 16; return v.f;
}
__device__ __forceinline__ float bfhi(unsigned p) {
    union { unsigned u; float f; } v; v.u = p & 0xFFFF0000u; return v.f;
}

// ---------------------------------------------------------------------------
// PREP: blocks [0,binGrid) bin edges; [binGrid,binGrid+64) W transpose+cvt;
//       rest: x -> bf16 + sentinel zero rows.
__global__ __launch_bounds__(1024) void prep_kernel(const int* __restrict__ row,
                                                    const int* __restrict__ col,
                                                    int* __restrict__ bincnt,
                                                    long long* __restrict__ binbuf,
                                                    int nE, int nbins, int binGrid,
                                                    const float2* __restrict__ x,
                                                    unsigned* __restrict__ xb, int nPairs,
                                                    const float* __restrict__ W1,
                                                    const float* __restrict__ W2,
                                                    unsigned short* __restrict__ Wt1,
                                                    unsigned short* __restrict__ Wt2,
                                                    unsigned* __restrict__ hb, int n) {
    __shared__ int bcnt[1024];
    __shared__ int bbase[1024];
    const int t = threadIdx.x;

    if (blockIdx.x < (unsigned)binGrid) {
        const int e0 = blockIdx.x * EPB + t * 8;
        if (t < nbins) bcnt[t] = 0;
        __syncthreads();

        int rr[8], cc[8], bin[8], pos[8];
        if (e0 + 8 <= nE) {
            int4 r0 = *(const int4*)&row[e0];
            int4 r1 = *(const int4*)&row[e0 + 4];
            int4 c0 = *(const int4*)&col[e0];
            int4 c1 = *(const int4*)&col[e0 + 4];
            rr[0] = r0.x; rr[1] = r0.y; rr[2] = r0.z; rr[3] = r0.w;
            rr[4] = r1.x; rr[5] = r1.y; rr[6] = r1.z; rr[7] = r1.w;
            cc[0] = c0.x; cc[1] = c0.y; cc[2] = c0.z; cc[3] = c0.w;
            cc[4] = c1.x; cc[5] = c1.y; cc[6] = c1.z; cc[7] = c1.w;
            #pragma unroll
            for (int k = 0; k < 8; ++k) {
                bin[k] = rr[k] >> BIN_SHIFT;
                pos[k] = atomicAdd(&bcnt[bin[k]], 1);
            }
        } else {
            #pragma unroll
            for (int k = 0; k < 8; ++k) {
                int e = e0 + k;
                if (e < nE) {
                    rr[k] = row[e]; cc[k] = col[e];
                    bin[k] = rr[k] >> BIN_SHIFT;
                    pos[k] = atomicAdd(&bcnt[bin[k]], 1);
                } else { pos[k] = -1; bin[k] = 0; rr[k] = 0; cc[k] = 0; }
            }
        }
        __syncthreads();

        if (t < nbins) {
            int c = bcnt[t];
            bbase[t] = (c > 0) ? atomicAdd(&bincnt[t << 4], c) : 0;
        }
        __syncthreads();

        #pragma unroll
        for (int k = 0; k < 8; ++k) {
            if (pos[k] >= 0) {
                int slot = bbase[bin[k]] + pos[k];
                if (slot < BINCAP)
                    binbuf[(size_t)bin[k] * BINCAP + slot] =
                        ((long long)cc[k] << 32) | (unsigned)rr[k];
            }
        }
    } else if (blockIdx.x < (unsigned)(binGrid + 64)) {
        int id = (blockIdx.x - binGrid) * 1024 + t;   // 0..65535
        int e = id & 32767;
        int c = e >> 8, k = e & 255;
        if (id < 32768) Wt1[c * 256 + k] = f2bf(W1[k * 128 + c]);
        else            Wt2[c * 256 + k] = f2bf(W2[k * 128 + c]);
    } else {
        int cb = blockIdx.x - binGrid - 64;
        if (cb == 0 && t < 64) {
            xb[((size_t)n << 6) + t] = 0;   // sentinel zero rows
            hb[((size_t)n << 6) + t] = 0;
        }
        int id = cb * 1024 + t;
        int stride = (gridDim.x - binGrid - 64) * 1024;
        for (int i = id; i < nPairs; i += stride) {
            float2 v = x[i];
            xb[i] = (unsigned)f2bf(v.x) | ((unsigned)f2bf(v.y) << 16);
        }
    }
}

// Phase 2: one block per bin; LDS counters; padded ELL (sentinel index n).
__global__ __launch_bounds__(256) void ellbuild_kernel(const long long* __restrict__ binbuf,
                                                       const int* __restrict__ bincnt,
                                                       int* __restrict__ cnt,
                                                       int* __restrict__ bucket, int n) {
    __shared__ int lcnt[1 << BIN_SHIFT];
    const int b = blockIdx.x, t = threadIdx.x;
    const int base = b << BIN_SHIFT;
    if (t < (1 << BIN_SHIFT)) lcnt[t] = 0;
    __syncthreads();
    int m = bincnt[b << 4];
    if (m > BINCAP) m = BINCAP;
    const long long* buf = binbuf + (size_t)b * BINCAP;
    for (int j = t; j < m; j += 256) {
        long long pk = buf[j];
        int r = (int)pk;            // low 32
        int c = (int)(pk >> 32);    // high 32
        int pos = atomicAdd(&lcnt[r - base], 1);
        if (pos < MAXDEG) bucket[((size_t)r << 6) + pos] = c;
    }
    __syncthreads();
    if (t < (1 << BIN_SHIFT)) {
        int node = base + t;
        if (node < n) {
            int c0 = lcnt[t];
            cnt[node] = c0;                       // true degree (for 1/deg)
            int c = c0 > MAXDEG ? MAXDEG : c0;
            int cp = (c + 15) & ~15;              // pad to multiple of 16
            for (int s = c; s < cp; ++s) bucket[((size_t)node << 6) + s] = n;
        }
    }
}

// ---------------------------------------------------------------------------
// 16-wide unconditional gather-accumulate (bucket row padded with sentinel)
__device__ __forceinline__ void gather16(const unsigned* __restrict__ feat,
                                         const int* __restrict__ bk, int j, unsigned lane,
                                         float& x0, float& x1, float& x2, float& x3,
                                         float& y0, float& y1, float& y2, float& y3) {
    int4 c0 = *(const int4*)&bk[j];
    int4 c1 = *(const int4*)&bk[j + 4];
    int4 c2 = *(const int4*)&bk[j + 8];
    int4 c3 = *(const int4*)&bk[j + 12];
    unsigned v0  = feat[((unsigned)c0.x << 6) + lane];
    unsigned v1  = feat[((unsigned)c0.y << 6) + lane];
    unsigned v2  = feat[((unsigned)c0.z << 6) + lane];
    unsigned v3  = feat[((unsigned)c0.w << 6) + lane];
    unsigned v4  = feat[((unsigned)c1.x << 6) + lane];
    unsigned v5  = feat[((unsigned)c1.y << 6) + lane];
    unsigned v6  = feat[((unsigned)c1.z << 6) + lane];
    unsigned v7  = feat[((unsigned)c1.w << 6) + lane];
    unsigned v8  = feat[((unsigned)c2.x << 6) + lane];
    unsigned v9  = feat[((unsigned)c2.y << 6) + lane];
    unsigned v10 = feat[((unsigned)c2.z << 6) + lane];
    unsigned v11 = feat[((unsigned)c2.w << 6) + lane];
    unsigned v12 = feat[((unsigned)c3.x << 6) + lane];
    unsigned v13 = feat[((unsigned)c3.y << 6) + lane];
    unsigned v14 = feat[((unsigned)c3.z << 6) + lane];
    unsigned v15 = feat[((unsigned)c3.w << 6) + lane];
    x0 += bflo(v0);  y0 += bfhi(v0);
    x1 += bflo(v1);  y1 += bfhi(v1);
    x2 += bflo(v2);  y2 += bfhi(v2);
    x3 += bflo(v3);  y3 += bfhi(v3);
    x0 += bflo(v4);  y0 += bfhi(v4);
    x1 += bflo(v5);  y1 += bfhi(v5);
    x2 += bflo(v6);  y2 += bfhi(v6);
    x3 += bflo(v7);  y3 += bfhi(v7);
    x0 += bflo(v8);  y0 += bfhi(v8);
    x1 += bflo(v9);  y1 += bfhi(v9);
    x2 += bflo(v10); y2 += bfhi(v10);
    x3 += bflo(v11); y3 += bfhi(v11);
    x0 += bflo(v12); y0 += bfhi(v12);
    x1 += bflo(v13); y1 += bfhi(v13);
    x2 += bflo(v14); y2 += bfhi(v14);
    x3 += bflo(v15); y3 += bfhi(v15);
}

// bf16 gather-mean: TWO nodes per wave, 16-wide unconditional batches.
__global__ __launch_bounds__(256) void agg_bf16_kernel(const unsigned* __restrict__ feat, // [n+1][64] dwords
                                                       const int* __restrict__ cnt,
                                                       const int* __restrict__ bucket,    // [n][64] padded
                                                       unsigned* __restrict__ agg, int n) {
    long long tid = (long long)blockIdx.x * blockDim.x + threadIdx.x;
    int w = (int)(tid >> 6);
    int iA = w * 2, iB = w * 2 + 1;
    if (iA >= n) return;
    const unsigned lane = (unsigned)tid & 63u;

    int dtA = cnt[iA];
    int dA = dtA > MAXDEG ? MAXDEG : dtA;
    int dpA = (dA + 15) & ~15;
    int dtB = 0, dpB = 0;
    if (iB < n) {
        dtB = cnt[iB];
        int dB = dtB > MAXDEG ? MAXDEG : dtB;
        dpB = (dB + 15) & ~15;
    }
    const int* bkA = bucket + ((size_t)iA << 6);
    const int* bkB = bucket + ((size_t)iB << 6);

    float ax0=0,ax1=0,ax2=0,ax3=0, ay0=0,ay1=0,ay2=0,ay3=0;
    float bx0=0,bx1=0,bx2=0,bx3=0, by0=0,by1=0,by2=0,by3=0;
    int jm = dpA > dpB ? dpA : dpB;
    for (int j = 0; j < jm; j += 16) {
        if (j < dpA) gather16(feat, bkA, j, lane, ax0,ax1,ax2,ax3, ay0,ay1,ay2,ay3);
        if (j < dpB) gather16(feat, bkB, j, lane, bx0,bx1,bx2,bx3, by0,by1,by2,by3);
    }

    float invA = (dtA > 0) ? 1.0f / (float)dtA : 0.0f;
    float rxA = ((ax0 + ax1) + (ax2 + ax3)) * invA;
    float ryA = ((ay0 + ay1) + (ay2 + ay3)) * invA;
    agg[((size_t)iA << 6) + lane] = (unsigned)f2bf(rxA) | ((unsigned)f2bf(ryA) << 16);
    if (iB < n) {
        float invB = (dtB > 0) ? 1.0f / (float)dtB : 0.0f;
        float rxB = ((bx0 + bx1) + (bx2 + bx3)) * invB;
        float ryB = ((by0 + by1) + (by2 + by3)) * invB;
        agg[((size_t)iB << 6) + lane] = (unsigned)f2bf(rxB) | ((unsigned)f2bf(ryB) << 16);
    }
}

// ---------------------------------------------------------------------------
// PERSISTENT pipelined MFMA GEMM: out[i,:] = act([self|agg][i,:] @ Wt^T + b)
// 256 thr (4 waves), 64-row tiles, K=256. Grid = 768 (3 blocks/CU); each
// block loops over tiles: ds_write A(t) -> barrier -> ISSUE A-loads(t+1) ->
// K-loop (loads hide under MFMA) -> epilogue. B fragments + bias loaded ONCE
// per block. bf16 epilogue staged via separate LDS buffer (exact stores).
template <bool RELU, bool OUTF32>
__global__ __launch_bounds__(256) void sage_mfma(const unsigned short* __restrict__ selfb, // [n][128]
                                                 const unsigned short* __restrict__ aggb,  // [n][128]
                                                 const unsigned short* __restrict__ Wtb,   // [128][256]
                                                 const float* __restrict__ bias,           // [128]
                                                 float* __restrict__ outf,
                                                 unsigned short* __restrict__ outb,
                                                 int n, int ntiles) {
    __shared__ short Alds[64 * 256];            // 32KB A tile
    __shared__ unsigned short Olds[64 * 128];   // 16KB bf16 out staging
    const int tid  = threadIdx.x;
    const int wave = tid >> 6;
    const int lane = tid & 63;
    const int r15  = lane & 15, g = lane >> 4;

    // ---- persistent: B fragments + bias, loaded once ----
    const int colbase = wave * 32;
    short8 bfr[2][8];
    #pragma unroll
    for (int cf = 0; cf < 2; ++cf) {
        const unsigned short* wp = Wtb + (size_t)(colbase + cf * 16 + r15) * 256;
        #pragma unroll
        for (int ks = 0; ks < 8; ++ks) {
            short4v lo = *(const short4v*)(wp + ks * 32 + 4 * g);
            short4v hi = *(const short4v*)(wp + ks * 32 + 16 + 4 * g);
            bfr[cf][ks] = __builtin_shufflevector(lo, hi, 0, 1, 2, 3, 4, 5, 6, 7);
        }
    }
    const float bv0 = bias[colbase + r15];
    const float bv1 = bias[colbase + 16 + r15];

    // per-thread staging decomposition (constant across tiles)
    short8 areg[8];
    auto loadA = [&](int t) {
        int rowbase = t * 64;
        #pragma unroll
        for (int it = 0; it < 8; ++it) {
            int id  = it * 256 + tid;
            int row = id >> 5, cin = id & 31;
            int rowG = rowbase + row; if (rowG >= n) rowG = n - 1;
            const unsigned short* src = (cin < 16)
                ? selfb + (size_t)rowG * D + cin * 8
                : aggb  + (size_t)rowG * D + (cin - 16) * 8;
            areg[it] = *(const short8*)src;
        }
    };

    int tile = blockIdx.x;
    if (tile < ntiles) loadA(tile);
    const int sw = (r15 & 7) << 4;

    for (; tile < ntiles; tile += gridDim.x) {
        __syncthreads();   // WAR: previous iteration's LDS readers done
        #pragma unroll
        for (int it = 0; it < 8; ++it) {
            int id  = it * 256 + tid;
            int row = id >> 5, cin = id & 31;
            int dch = cin ^ (row & 7);
            *(short8*)&Alds[row * 256 + dch * 8] = areg[it];
        }
        __syncthreads();   // A visible

        int nt = tile + gridDim.x;
        if (nt < ntiles) loadA(nt);    // issue next-tile loads; land under K-loop

        float4v acc[4][2];
        #pragma unroll
        for (int rf = 0; rf < 4; ++rf) {
            acc[rf][0] = (float4v){bv0, bv0, bv0, bv0};
            acc[rf][1] = (float4v){bv1, bv1, bv1, bv1};
        }

        #pragma unroll
        for (int ks = 0; ks < 8; ++ks) {
            #pragma unroll
            for (int rf = 0; rf < 4; ++rf) {
                const char* pr = (const char*)&Alds[(rf * 16 + r15) * 256];
                short4v lo = *(const short4v*)(pr + ((ks * 64 + 8 * g) ^ sw));
                short4v hi = *(const short4v*)(pr + ((ks * 64 + 8 * g + 32) ^ sw));
                short8 af = __builtin_shufflevector(lo, hi, 0, 1, 2, 3, 4, 5, 6, 7);
                acc[rf][0] = __builtin_amdgcn_mfma_f32_16x16x32_bf16(af, bfr[0][ks], acc[rf][0], 0, 0, 0);
                acc[rf][1] = __builtin_amdgcn_mfma_f32_16x16x32_bf16(af, bfr[1][ks], acc[rf][1], 0, 0, 0);
            }
        }

        int rowbase = tile * 64;
        if (OUTF32) {
            // direct stores: 16 consecutive f32 per 16-lane group = exact 64B
            #pragma unroll
            for (int rf = 0; rf < 4; ++rf)
                #pragma unroll
                for (int cf = 0; cf < 2; ++cf)
                    #pragma unroll
                    for (int r = 0; r < 4; ++r) {
                        int row = rowbase + rf * 16 + g * 4 + r;
                        int col = colbase + cf * 16 + r15;
                        if (row < n) {
                            float v = acc[rf][cf][r];
                            if (RELU) v = (v > 0.0f) ? v : 0.0f;
                            outf[(size_t)row * D + col] = v;
                        }
                    }
        } else {
            // stage bf16 tile in Olds, then exact row-contiguous stores
            #pragma unroll
            for (int rf = 0; rf < 4; ++rf)
                #pragma unroll
                for (int cf = 0; cf < 2; ++cf)
                    #pragma unroll
                    for (int r = 0; r < 4; ++r) {
                        float v = acc[rf][cf][r];
                        if (RELU) v = (v > 0.0f) ? v : 0.0f;
                        Olds[(rf * 16 + g * 4 + r) * 128 + colbase + cf * 16 + r15] = f2bf(v);
                    }
            __syncthreads();   // Olds complete (also: all waves done reading Alds)
            #pragma unroll
            for (int it = 0; it < 4; ++it) {
                int id = it * 256 + tid;           // 64 rows x 16 short8-chunks
                int r = id >> 4, ch = id & 15;
                int rowG = rowbase + r;
                if (rowG < n)
                    *(short8*)&outb[(size_t)rowG * D + ch * 8] = *(const short8*)&Olds[r * 128 + ch * 8];
            }
        }
    }
}

// ---------------------------------------------------------------------------
extern "C" void kernel_launch(void* const* d_in, const int* in_sizes, int n_in,
                              void* d_out, int out_size, void* d_ws, size_t ws_size,
                              hipStream_t stream) {
    const float* x  = (const float*)d_in[0];
    const int*   ei = (const int*)d_in[1];
    const float* W1 = (const float*)d_in[2];
    const float* b1 = (const float*)d_in[3];
    const float* W2 = (const float*)d_in[4];
    const float* b2 = (const float*)d_in[5];
    float* out = (float*)d_out;

    const int n  = in_sizes[0] / D;   // 100000
    const int nE = in_sizes[1] / 2;   // 1000000
    const int* row = ei;
    const int* col = ei + nE;
    const int nbins = (n + (1 << BIN_SHIFT) - 1) >> BIN_SHIFT;   // 782

    auto aup = [](size_t v) { return (v + 63) & ~(size_t)63; };
    int* wsI = (int*)d_ws;
    size_t o = 0;
    int* cnt    = wsI + o; o = aup(o + (size_t)n);
    int* bucket = wsI + o; o = aup(o + ((size_t)n << 6));               // [n][64]
    unsigned* xb   = (unsigned*)(wsI + o); o = aup(o + (size_t)(n + 1) * 64); // +1 sentinel row
    unsigned* hb   = (unsigned*)(wsI + o); o = aup(o + (size_t)(n + 1) * 64);
    unsigned* aggb = (unsigned*)(wsI + o); o = aup(o + (size_t)n * 64);
    unsigned short* Wt1 = (unsigned short*)(wsI + o); o = aup(o + 16384);
    unsigned short* Wt2 = (unsigned short*)(wsI + o); o = aup(o + 16384);
    int* bincnt = wsI + o; o = aup(o + (size_t)nbins * 16);             // 1 counter / 64B
    // binbuf overlaps aggb (dead before first agg): 782*2048*8B = 12.8MB < 25.6MB
    long long* binbuf = (long long*)aggb;

    const int B = 256;
    const int binGrid = (nE + EPB - 1) / EPB;                           // 123
    const int aggGrid = (int)((((long long)(n + 1) / 2) * 64 + B - 1) / B);
    const int ntiles  = (n + 63) / 64;                                  // 1563
    const int mmGrid  = ntiles < 768 ? ntiles : 768;                    // 3 blocks/CU

    // prep: binning + W transpose + x conversion, one kernel
    hipMemsetAsync(bincnt, 0, (size_t)nbins * 16 * sizeof(int), stream);
    prep_kernel<<<binGrid + 64 + 512, 1024, 0, stream>>>(
        row, col, bincnt, binbuf, nE, nbins, binGrid,
        (const float2*)x, xb, n * 64, W1, W2, Wt1, Wt2, hb, n);
    ellbuild_kernel<<<nbins, B, 0, stream>>>(binbuf, bincnt, cnt, bucket, n);

    // layer 1
    agg_bf16_kernel<<<aggGrid, B, 0, stream>>>(xb, cnt, bucket, aggb, n);
    sage_mfma<true, false><<<mmGrid, B, 0, stream>>>(
        (const unsigned short*)xb, (const unsigned short*)aggb, Wt1, b1,
        nullptr, (unsigned short*)hb, n, ntiles);

    // layer 2
    agg_bf16_kernel<<<aggGrid, B, 0, stream>>>(hb, cnt, bucket, aggb, n);
    sage_mfma<false, true><<<mmGrid, B, 0, stream>>>(
        (const unsigned short*)hb, (const unsigned short*)aggb, Wt2, b2,
        out, nullptr, n, ntiles);
}